// Round 5
// baseline (100.573 us; speedup 1.0000x reference)
//
#include <hip/hip_runtime.h>
#include <hip/hip_bf16.h>

#define NN 4096
#define NB 32
#define NUPPER 528
#define NLOWER 496
#define BLK_ELEMS 16384      // 128*128

typedef __bf16 v8bf __attribute__((ext_vector_type(8)));
typedef __bf16 v4bf __attribute__((ext_vector_type(4)));
typedef float  v4f  __attribute__((ext_vector_type(4)));

typedef __attribute__((address_space(1))) const unsigned int* as1p;
typedef __attribute__((address_space(3))) unsigned int* as3p;
#define GLOAD16(DST_LDS, SRC_G) \
    __builtin_amdgcn_global_load_lds((as1p)(const void*)(SRC_G), (as3p)(void*)(DST_LDS), 16, 0, 0)

// ---------------- prep: bf16-pack A, bf16-transpose-pack B, zero lower C ----
__global__ __launch_bounds__(256)
void trimm_prep(const float* __restrict__ A, const float* __restrict__ B,
                float* __restrict__ C,
                __bf16* __restrict__ Apk, __bf16* __restrict__ Bpk) {
    const int p = blockIdx.x;
    const int t = threadIdx.x;
    __shared__ __bf16 Ls[128][132];

    if (p < NUPPER) {
        // ---- A block (bi, q) ----
        int bi = 0;
        while ((bi + 1) * 32 - ((bi + 1) * bi) / 2 <= p) ++bi;
        const int base = bi * 32 - (bi * (bi - 1)) / 2;
        const int q = bi + (p - base);
        const float* src = A + (long)bi * 128 * NN + (long)q * 128;
        __bf16* dst = Apk + (long)p * BLK_ELEMS;
        #pragma unroll
        for (int i = 0; i < 16; ++i) {
            int s = i * 256 + t, r = s >> 5, c4 = (s & 31) << 2;
            v4f v = __builtin_nontemporal_load(
                reinterpret_cast<const v4f*>(&src[(long)r * NN + c4]));
            v4bf pk;
            pk[0] = (__bf16)v[0]; pk[1] = (__bf16)v[1];
            pk[2] = (__bf16)v[2]; pk[3] = (__bf16)v[3];
            *reinterpret_cast<v4bf*>(&dst[r * 128 + c4]) = pk;
        }
        return;
    }
    if (p < 2 * NUPPER) {
        // ---- B block (q, bj) -> Bpk[n][k] transposed, idx bj*(bj+1)/2+q ----
        const int p2 = p - NUPPER;
        int bj = 0;
        while (((bj + 1) * (bj + 2)) / 2 <= p2) ++bj;
        const int q = p2 - (bj * (bj + 1)) / 2;
        const float* src = B + (long)q * 128 * NN + (long)bj * 128;
        __bf16* dst = Bpk + (long)p2 * BLK_ELEMS;
        #pragma unroll
        for (int i = 0; i < 16; ++i) {
            int s = i * 256 + t, k = s >> 5, n4 = (s & 31) << 2;
            v4f v = __builtin_nontemporal_load(
                reinterpret_cast<const v4f*>(&src[(long)k * NN + n4]));
            Ls[k][n4 + 0] = (__bf16)v[0]; Ls[k][n4 + 1] = (__bf16)v[1];
            Ls[k][n4 + 2] = (__bf16)v[2]; Ls[k][n4 + 3] = (__bf16)v[3];
        }
        __syncthreads();
        #pragma unroll
        for (int i = 0; i < 8; ++i) {
            int n = i * 16 + (t >> 4), k0 = (t & 15) << 3;
            v8bf o;
            #pragma unroll
            for (int j = 0; j < 8; ++j) o[j] = Ls[k0 + j][n];
            *reinterpret_cast<v8bf*>(&dst[n * 128 + k0]) = o;
        }
        return;
    }
    // ---- zero-fill strictly-lower C tile (streaming, nt) ----
    const int z = p - 2 * NUPPER;
    int bi = 1;
    while (((bi + 1) * bi) / 2 <= z) ++bi;
    const int bj = z - (bi * (bi - 1)) / 2;
    const long brow = (long)bi * 128, bcol = (long)bj * 128;
    const v4f zv = (v4f){0.f, 0.f, 0.f, 0.f};
    #pragma unroll
    for (int i = 0; i < 16; ++i) {
        int s = i * 256 + t, r = s >> 5, c4 = (s & 31) << 2;
        __builtin_nontemporal_store(zv,
            reinterpret_cast<v4f*>(&C[(brow + r) * NN + bcol + c4]));
    }
}

// ---------------- main MFMA kernel: 128^2 tile, BK=64, gload_lds + swizzle --
__global__ __launch_bounds__(256, 4)
void trimm_mm(const __bf16* __restrict__ Apk, const __bf16* __restrict__ Bpk,
              float* __restrict__ C, __bf16* __restrict__ part, int umax) {
    const int id = blockIdx.x;
    const int t  = threadIdx.x;

    // map id -> (d desc, bi, chunk c); slot base for partials
    int rem = id, d, S, sb = 0;
    for (d = 31;; --d) {
        S = (d + umax) / umax;               // ceil((d+1)/umax)
        int cnt = (32 - d) * S;
        if (rem < cnt) break;
        rem -= cnt;
        sb += (32 - d) * (S - 1);
    }
    const int bi = rem / S, c = rem % S;
    const int bj = bi + d;
    const int U  = d + 1;
    const int ubase = U / S, uremu = U % S;
    const int units = ubase + ((c < uremu) ? 1 : 0);
    const int qoff  = c * ubase + ((c < uremu) ? c : uremu);
    const int nt    = units * 2;                            // BK=64 steps
    const int q0    = bi + qoff;
    const int abase0 = bi * 32 - (bi * (bi - 1)) / 2 - bi;  // A idx = abase0+q
    const int bbase0 = (bj * (bj + 1)) / 2;                 // B idx = bbase0+q

    __shared__ __bf16 AsF[8192];   // logical [128 rows][64 k], XOR-swizzled
    __shared__ __bf16 BsF[8192];

    const int lane = t & 63, wave = t >> 6;
    const int wm = (wave >> 1) << 6, wn = (wave & 1) << 6;
    const int l15 = lane & 15, g = lane >> 4;
    const int swz = (l15 & 7) << 3;
    const int srow8 = lane >> 3;
    const int sslot = ((lane & 7) ^ srow8) << 3;

    v4f acc[4][4];
    #pragma unroll
    for (int mf = 0; mf < 4; ++mf)
        #pragma unroll
        for (int nf = 0; nf < 4; ++nf)
            acc[mf][nf] = (v4f){0.f, 0.f, 0.f, 0.f};

    for (int tk = 0; tk < nt; ++tk) {
        const int q   = q0 + (tk >> 1);
        const int kin = (tk & 1) << 6;
        const long aoff = ((long)(abase0 + q) << 14) + kin + sslot;
        const long boff = ((long)(bbase0 + q) << 14) + kin + sslot;
        #pragma unroll
        for (int i = 0; i < 4; ++i) {
            const int seg = (wave << 2) + i;
            const long r128 = (long)(seg * 8 + srow8) << 7;
            GLOAD16(AsF + (seg << 9), Apk + aoff + r128);
            GLOAD16(BsF + (seg << 9), Bpk + boff + r128);
        }
        __syncthreads();

        #pragma unroll
        for (int kc = 0; kc < 2; ++kc) {
            v8bf af[4], bfv[4];
            #pragma unroll
            for (int mf = 0; mf < 4; ++mf) {
                int row = wm + mf * 16 + l15;
                af[mf] = *reinterpret_cast<const v8bf*>(
                    &AsF[(row * 64 + kc * 32 + g * 8) ^ swz]);
            }
            #pragma unroll
            for (int nf = 0; nf < 4; ++nf) {
                int row = wn + nf * 16 + l15;
                bfv[nf] = *reinterpret_cast<const v8bf*>(
                    &BsF[(row * 64 + kc * 32 + g * 8) ^ swz]);
            }
            #pragma unroll
            for (int mf = 0; mf < 4; ++mf)
                #pragma unroll
                for (int nf = 0; nf < 4; ++nf)
                    acc[mf][nf] = __builtin_amdgcn_mfma_f32_16x16x32_bf16(
                        af[mf], bfv[nf], acc[mf][nf], 0, 0, 0);
        }
        __syncthreads();
    }

    // epilogue: C/D layout col=lane&15, row=(lane>>4)*4+reg
    if (c == 0) {
        float* outp = C + (long)bi * 128 * NN + (long)bj * 128;
        const bool merged = (S > 1);   // merge re-reads C: keep cached
        #pragma unroll
        for (int mf = 0; mf < 4; ++mf)
            #pragma unroll
            for (int nf = 0; nf < 4; ++nf) {
                int row = wm + mf * 16 + g * 4;
                int col = wn + nf * 16 + l15;
                #pragma unroll
                for (int r = 0; r < 4; ++r) {
                    float* p = &outp[(long)(row + r) * NN + col];
                    if (merged) *p = acc[mf][nf][r];
                    else        __builtin_nontemporal_store(acc[mf][nf][r], p);
                }
            }
    } else {
        __bf16* pp = part + (long)(sb + bi * (S - 1) + (c - 1)) * BLK_ELEMS;
        #pragma unroll
        for (int mf = 0; mf < 4; ++mf)
            #pragma unroll
            for (int nf = 0; nf < 4; ++nf) {
                int row = wm + mf * 16 + g * 4;
                int col = wn + nf * 16 + l15;
                #pragma unroll
                for (int r = 0; r < 4; ++r)
                    pp[(row + r) * 128 + col] = (__bf16)acc[mf][nf][r];
            }
    }
}

// ---------------- merge: C += partials (fixed order) ------------------------
__global__ __launch_bounds__(256)
void trimm_merge(float* __restrict__ C, const __bf16* __restrict__ part, int umax) {
    int rem = blockIdx.x;
    const int t = threadIdx.x;
    int d, S, sb = 0;
    for (d = 31;; --d) {
        S = (d + umax) / umax;
        int cnt = 32 - d;
        if (rem < cnt) break;
        rem -= cnt;
        sb += (32 - d) * (S - 1);
    }
    if (S == 1) return;
    const int bi = rem, bj = bi + d;
    const int ns = S - 1;
    const __bf16* pp = part + (long)(sb + bi * ns) * BLK_ELEMS;
    float* cp = C + (long)bi * 128 * NN + (long)bj * 128;

    #pragma unroll
    for (int i = 0; i < 8; ++i) {
        int e = (i * 256 + t) * 8;          // 8 elems per thread per iter
        int r = e >> 7, c8 = e & 127;
        v4f lo = *reinterpret_cast<v4f*>(&cp[(long)r * NN + c8]);
        v4f hi = *reinterpret_cast<v4f*>(&cp[(long)r * NN + c8 + 4]);
        for (int q = 0; q < ns; ++q) {
            v8bf w = *reinterpret_cast<const v8bf*>(&pp[q * BLK_ELEMS + r * 128 + c8]);
            lo[0] += (float)w[0]; lo[1] += (float)w[1];
            lo[2] += (float)w[2]; lo[3] += (float)w[3];
            hi[0] += (float)w[4]; hi[1] += (float)w[5];
            hi[2] += (float)w[6]; hi[3] += (float)w[7];
        }
        __builtin_nontemporal_store(lo, reinterpret_cast<v4f*>(&cp[(long)r * NN + c8]));
        __builtin_nontemporal_store(hi, reinterpret_cast<v4f*>(&cp[(long)r * NN + c8 + 4]));
    }
}

// ---------------- fallback (ws too small): fused convert-stage kernel -------
#define LDST 40
__global__ __launch_bounds__(256)
void trimm_fb(const float* __restrict__ A, const float* __restrict__ B,
              float* __restrict__ C) {
    const int id = blockIdx.x, t = threadIdx.x;
    if (id >= NUPPER) {
        int z = id - NUPPER;
        int bi = 1;
        while (((bi + 1) * bi) / 2 <= z) ++bi;
        int bj = z - (bi * (bi - 1)) / 2;
        const long brow = (long)bi * 128, bcol = (long)bj * 128;
        const v4f zv = (v4f){0.f, 0.f, 0.f, 0.f};
        #pragma unroll
        for (int i = 0; i < 16; ++i) {
            int s = i * 256 + t, r = s >> 5, c4 = (s & 31) << 2;
            *reinterpret_cast<v4f*>(&C[(brow + r) * NN + bcol + c4]) = zv;
        }
        return;
    }
    int q = (NUPPER - 1) - id;
    int d = 0;
    while (d < 31 && 32 * (d + 1) - (d + 1) * d / 2 <= q) ++d;
    const int bi = q - (32 * d - d * (d - 1) / 2);
    const int bj = bi + d;
    const long brow = (long)bi * 128, bcol = (long)bj * 128;
    __shared__ __bf16 As[128][LDST];
    __shared__ __bf16 Bs[128][LDST];
    const int lane = t & 63, wave = t >> 6;
    const int wm = (wave >> 1) * 64, wn = (wave & 1) * 64;
    const int l15 = lane & 15, g = lane >> 4;
    const int arow = t >> 3, akc = (t & 7) << 2;
    const int bn = t & 31, bkc = (t >> 5) << 2;
    v4f acc[4][4];
    #pragma unroll
    for (int mf = 0; mf < 4; ++mf)
        #pragma unroll
        for (int nf = 0; nf < 4; ++nf) acc[mf][nf] = (v4f){0.f,0.f,0.f,0.f};
    const long k0 = brow;
    const int nt = (d + 1) * 4;
    for (int tk = 0; tk < nt; ++tk) {
        const long kt = k0 + (long)tk * 32;
        #pragma unroll
        for (int i = 0; i < 4; ++i) {
            v4f a4 = *reinterpret_cast<const v4f*>(
                &A[(brow + arow + 32 * i) * NN + kt + akc]);
            v4bf pk;
            pk[0]=(__bf16)a4[0]; pk[1]=(__bf16)a4[1]; pk[2]=(__bf16)a4[2]; pk[3]=(__bf16)a4[3];
            *reinterpret_cast<v4bf*>(&As[arow + 32 * i][akc]) = pk;
        }
        {
            float tmp[4][4];
            #pragma unroll
            for (int jj = 0; jj < 4; ++jj) {
                const float* Brow = B + (kt + bkc + jj) * NN + bcol + bn;
                #pragma unroll
                for (int j = 0; j < 4; ++j) tmp[j][jj] = Brow[32 * j];
            }
            #pragma unroll
            for (int j = 0; j < 4; ++j) {
                v4bf pk;
                pk[0]=(__bf16)tmp[j][0]; pk[1]=(__bf16)tmp[j][1];
                pk[2]=(__bf16)tmp[j][2]; pk[3]=(__bf16)tmp[j][3];
                *reinterpret_cast<v4bf*>(&Bs[bn + 32 * j][bkc]) = pk;
            }
        }
        __syncthreads();
        v8bf af[4], bfr[4];
        #pragma unroll
        for (int mf = 0; mf < 4; ++mf)
            af[mf] = *reinterpret_cast<const v8bf*>(&As[wm + mf*16 + l15][g*8]);
        #pragma unroll
        for (int nf = 0; nf < 4; ++nf)
            bfr[nf] = *reinterpret_cast<const v8bf*>(&Bs[wn + nf*16 + l15][g*8]);
        #pragma unroll
        for (int mf = 0; mf < 4; ++mf)
            #pragma unroll
            for (int nf = 0; nf < 4; ++nf)
                acc[mf][nf] = __builtin_amdgcn_mfma_f32_16x16x32_bf16(
                    af[mf], bfr[nf], acc[mf][nf], 0, 0, 0);
        __syncthreads();
    }
    #pragma unroll
    for (int mf = 0; mf < 4; ++mf)
        #pragma unroll
        for (int nf = 0; nf < 4; ++nf) {
            long row = brow + wm + mf * 16 + g * 4;
            long col = bcol + wn + nf * 16 + l15;
            #pragma unroll
            for (int r = 0; r < 4; ++r)
                C[(row + r) * NN + col] = acc[mf][nf][r];
        }
}

static void split_counts(int umax, int* nwork, int* slots) {
    int w = 0, s = 0;
    for (int d = 0; d < 32; ++d) {
        int S = (d + umax) / umax;
        w += (32 - d) * S;
        s += (32 - d) * (S - 1);
    }
    *nwork = w; *slots = s;
}

extern "C" void kernel_launch(void* const* d_in, const int* in_sizes, int n_in,
                              void* d_out, int out_size, void* d_ws, size_t ws_size,
                              hipStream_t stream) {
    const float* A = (const float*)d_in[0];
    const float* B = (const float*)d_in[1];
    float* C = (float*)d_out;

    const size_t needAB = 2UL * NUPPER * BLK_ELEMS * sizeof(__bf16);  // ~33 MB

    // pick the finest split the workspace allows
    const int cand[3] = {8, 16, 1000};
    int umax = 0, nwork = 0, slots = 0;
    for (int i = 0; i < 3; ++i) {
        int w, s;
        split_counts(cand[i], &w, &s);
        size_t need = needAB + (size_t)s * BLK_ELEMS * sizeof(__bf16);
        if (ws_size >= need) { umax = cand[i]; nwork = w; slots = s; break; }
    }

    if (umax) {
        __bf16* Apk = (__bf16*)d_ws;
        __bf16* Bpk = Apk + (size_t)NUPPER * BLK_ELEMS;
        __bf16* part = Bpk + (size_t)NUPPER * BLK_ELEMS;
        trimm_prep<<<dim3(2 * NUPPER + NLOWER), 256, 0, stream>>>(A, B, C, Apk, Bpk);
        trimm_mm<<<dim3(nwork), 256, 0, stream>>>(Apk, Bpk, C, part, umax);
        if (slots > 0)
            trimm_merge<<<dim3(NUPPER), 256, 0, stream>>>(C, part, umax);
    } else {
        trimm_fb<<<dim3(NUPPER + NLOWER), 256, 0, stream>>>(A, B, C);
    }
}

// Round 6
// 86.470 us; speedup vs baseline: 1.1631x; 1.1631x over previous
//
#include <hip/hip_runtime.h>
#include <hip/hip_bf16.h>

#define NN 4096
#define NB 32
#define NUPPER 528
#define NLOWER 496
#define BLK_ELEMS 16384      // 128*128

typedef __bf16 v8bf __attribute__((ext_vector_type(8)));
typedef __bf16 v4bf __attribute__((ext_vector_type(4)));
typedef float  v4f  __attribute__((ext_vector_type(4)));

typedef __attribute__((address_space(1))) const unsigned int* as1p;
typedef __attribute__((address_space(3))) unsigned int* as3p;
#define GLOAD16(DST_LDS, SRC_G) \
    __builtin_amdgcn_global_load_lds((as1p)(const void*)(SRC_G), (as3p)(void*)(DST_LDS), 16, 0, 0)

// ---------------- prep: bf16-pack A, bf16-transpose-pack B, zero lower C ----
__global__ __launch_bounds__(256)
void trimm_prep(const float* __restrict__ A, const float* __restrict__ B,
                float* __restrict__ C,
                __bf16* __restrict__ Apk, __bf16* __restrict__ Bpk) {
    const int p = blockIdx.x;
    const int t = threadIdx.x;
    __shared__ __bf16 Ls[128][132];

    if (p < NUPPER) {
        // ---- A block (bi, q) ----
        int bi = 0;
        while ((bi + 1) * 32 - ((bi + 1) * bi) / 2 <= p) ++bi;
        const int base = bi * 32 - (bi * (bi - 1)) / 2;
        const int q = bi + (p - base);
        const float* src = A + (long)bi * 128 * NN + (long)q * 128;
        __bf16* dst = Apk + (long)p * BLK_ELEMS;
        #pragma unroll
        for (int i = 0; i < 16; ++i) {
            int s = i * 256 + t, r = s >> 5, c4 = (s & 31) << 2;
            v4f v = __builtin_nontemporal_load(
                reinterpret_cast<const v4f*>(&src[(long)r * NN + c4]));
            v4bf pk;
            pk[0] = (__bf16)v[0]; pk[1] = (__bf16)v[1];
            pk[2] = (__bf16)v[2]; pk[3] = (__bf16)v[3];
            *reinterpret_cast<v4bf*>(&dst[r * 128 + c4]) = pk;
        }
        return;
    }
    if (p < 2 * NUPPER) {
        // ---- B block (q, bj) -> Bpk[n][k] transposed, idx bj*(bj+1)/2+q ----
        const int p2 = p - NUPPER;
        int bj = 0;
        while (((bj + 1) * (bj + 2)) / 2 <= p2) ++bj;
        const int q = p2 - (bj * (bj + 1)) / 2;
        const float* src = B + (long)q * 128 * NN + (long)bj * 128;
        __bf16* dst = Bpk + (long)p2 * BLK_ELEMS;
        #pragma unroll
        for (int i = 0; i < 16; ++i) {
            int s = i * 256 + t, k = s >> 5, n4 = (s & 31) << 2;
            v4f v = __builtin_nontemporal_load(
                reinterpret_cast<const v4f*>(&src[(long)k * NN + n4]));
            Ls[k][n4 + 0] = (__bf16)v[0]; Ls[k][n4 + 1] = (__bf16)v[1];
            Ls[k][n4 + 2] = (__bf16)v[2]; Ls[k][n4 + 3] = (__bf16)v[3];
        }
        __syncthreads();
        #pragma unroll
        for (int i = 0; i < 8; ++i) {
            int n = i * 16 + (t >> 4), k0 = (t & 15) << 3;
            v8bf o;
            #pragma unroll
            for (int j = 0; j < 8; ++j) o[j] = Ls[k0 + j][n];
            *reinterpret_cast<v8bf*>(&dst[n * 128 + k0]) = o;
        }
        return;
    }
    // ---- zero-fill strictly-lower C tile (streaming, nt) ----
    const int z = p - 2 * NUPPER;
    int bi = 1;
    while (((bi + 1) * bi) / 2 <= z) ++bi;
    const int bj = z - (bi * (bi - 1)) / 2;
    const long brow = (long)bi * 128, bcol = (long)bj * 128;
    const v4f zv = (v4f){0.f, 0.f, 0.f, 0.f};
    #pragma unroll
    for (int i = 0; i < 16; ++i) {
        int s = i * 256 + t, r = s >> 5, c4 = (s & 31) << 2;
        __builtin_nontemporal_store(zv,
            reinterpret_cast<v4f*>(&C[(brow + r) * NN + bcol + c4]));
    }
}

// ------- main MFMA kernel: 128^2 tile, BK=64, gload_lds + swizzle + DBUF ----
__global__ __launch_bounds__(256, 2)
void trimm_mm(const __bf16* __restrict__ Apk, const __bf16* __restrict__ Bpk,
              float* __restrict__ C, __bf16* __restrict__ part, int umax) {
    const int id = blockIdx.x;
    const int t  = threadIdx.x;

    // map id -> (d desc, bi, chunk c); slot base for partials
    int rem = id, d, S, sb = 0;
    for (d = 31;; --d) {
        S = (d + umax) / umax;               // ceil((d+1)/umax)
        int cnt = (32 - d) * S;
        if (rem < cnt) break;
        rem -= cnt;
        sb += (32 - d) * (S - 1);
    }
    const int bi = rem / S, c = rem % S;
    const int bj = bi + d;
    const int U  = d + 1;
    const int ubase = U / S, uremu = U % S;
    const int units = ubase + ((c < uremu) ? 1 : 0);
    const int qoff  = c * ubase + ((c < uremu) ? c : uremu);
    const int nt    = units * 2;                            // BK=64 steps
    const int q0    = bi + qoff;
    const int abase0 = bi * 32 - (bi * (bi - 1)) / 2 - bi;  // A idx = abase0+q
    const int bbase0 = (bj * (bj + 1)) / 2;                 // B idx = bbase0+q

    __shared__ __bf16 AsF[2][8192];   // logical [128 rows][64 k], XOR-swizzled
    __shared__ __bf16 BsF[2][8192];

    const int lane = t & 63, wave = t >> 6;
    const int wm = (wave >> 1) << 6, wn = (wave & 1) << 6;
    const int l15 = lane & 15, g = lane >> 4;
    const int swz = (l15 & 7) << 3;
    const int srow8 = lane >> 3;
    const int sslot = ((lane & 7) ^ srow8) << 3;

    v4f acc[4][4];
    #pragma unroll
    for (int mf = 0; mf < 4; ++mf)
        #pragma unroll
        for (int nf = 0; nf < 4; ++nf)
            acc[mf][nf] = (v4f){0.f, 0.f, 0.f, 0.f};

    #define STAGE(BUF, TK)                                                    \
        {                                                                     \
            const int q   = q0 + ((TK) >> 1);                                 \
            const int kin = ((TK) & 1) << 6;                                  \
            const long aoff = ((long)(abase0 + q) << 14) + kin + sslot;       \
            const long boff = ((long)(bbase0 + q) << 14) + kin + sslot;       \
            _Pragma("unroll")                                                 \
            for (int i = 0; i < 4; ++i) {                                     \
                const int seg = (wave << 2) + i;                              \
                const long r128 = (long)(seg * 8 + srow8) << 7;               \
                GLOAD16(&AsF[BUF][seg << 9], Apk + aoff + r128);              \
                GLOAD16(&BsF[BUF][seg << 9], Bpk + boff + r128);              \
            }                                                                 \
        }

    // prologue: stage tile 0, wait (syncthreads drains vmcnt)
    STAGE(0, 0);
    __syncthreads();

    int cur = 0;
    for (int tk = 0; tk < nt; ++tk) {
        // issue next-tile loads BEFORE computing current: latency hides
        // under ds_read+MFMA; the end-of-iter barrier drains them.
        if (tk + 1 < nt) STAGE(cur ^ 1, tk + 1);

        #pragma unroll
        for (int kc = 0; kc < 2; ++kc) {
            v8bf af[4], bfv[4];
            #pragma unroll
            for (int mf = 0; mf < 4; ++mf) {
                int row = wm + mf * 16 + l15;
                af[mf] = *reinterpret_cast<const v8bf*>(
                    &AsF[cur][(row * 64 + kc * 32 + g * 8) ^ swz]);
            }
            #pragma unroll
            for (int nf = 0; nf < 4; ++nf) {
                int row = wn + nf * 16 + l15;
                bfv[nf] = *reinterpret_cast<const v8bf*>(
                    &BsF[cur][(row * 64 + kc * 32 + g * 8) ^ swz]);
            }
            #pragma unroll
            for (int mf = 0; mf < 4; ++mf)
                #pragma unroll
                for (int nf = 0; nf < 4; ++nf)
                    acc[mf][nf] = __builtin_amdgcn_mfma_f32_16x16x32_bf16(
                        af[mf], bfv[nf], acc[mf][nf], 0, 0, 0);
        }
        __syncthreads();   // drains vmcnt(0): next tile staged & reads done
        cur ^= 1;
    }
    #undef STAGE

    // epilogue: C/D layout col=lane&15, row=(lane>>4)*4+reg
    if (c == 0) {
        float* outp = C + (long)bi * 128 * NN + (long)bj * 128;
        const bool merged = (S > 1);   // merge re-reads C: keep cached
        #pragma unroll
        for (int mf = 0; mf < 4; ++mf)
            #pragma unroll
            for (int nf = 0; nf < 4; ++nf) {
                int row = wm + mf * 16 + g * 4;
                int col = wn + nf * 16 + l15;
                #pragma unroll
                for (int r = 0; r < 4; ++r) {
                    float* p = &outp[(long)(row + r) * NN + col];
                    if (merged) *p = acc[mf][nf][r];
                    else        __builtin_nontemporal_store(acc[mf][nf][r], p);
                }
            }
    } else {
        __bf16* pp = part + (long)(sb + bi * (S - 1) + (c - 1)) * BLK_ELEMS;
        #pragma unroll
        for (int mf = 0; mf < 4; ++mf)
            #pragma unroll
            for (int nf = 0; nf < 4; ++nf) {
                int row = wm + mf * 16 + g * 4;
                int col = wn + nf * 16 + l15;
                #pragma unroll
                for (int r = 0; r < 4; ++r)
                    pp[(row + r) * 128 + col] = (__bf16)acc[mf][nf][r];
            }
    }
}

// ---------------- merge: C += partials (fixed order) ------------------------
__global__ __launch_bounds__(256)
void trimm_merge(float* __restrict__ C, const __bf16* __restrict__ part, int umax) {
    int rem = blockIdx.x;
    const int t = threadIdx.x;
    int d, S, sb = 0;
    for (d = 31;; --d) {
        S = (d + umax) / umax;
        int cnt = 32 - d;
        if (rem < cnt) break;
        rem -= cnt;
        sb += (32 - d) * (S - 1);
    }
    if (S == 1) return;
    const int bi = rem, bj = bi + d;
    const int ns = S - 1;
    const __bf16* pp = part + (long)(sb + bi * ns) * BLK_ELEMS;
    float* cp = C + (long)bi * 128 * NN + (long)bj * 128;

    #pragma unroll
    for (int i = 0; i < 8; ++i) {
        int e = (i * 256 + t) * 8;          // 8 elems per thread per iter
        int r = e >> 7, c8 = e & 127;
        v4f lo = *reinterpret_cast<v4f*>(&cp[(long)r * NN + c8]);
        v4f hi = *reinterpret_cast<v4f*>(&cp[(long)r * NN + c8 + 4]);
        for (int q = 0; q < ns; ++q) {
            v8bf w = *reinterpret_cast<const v8bf*>(&pp[q * BLK_ELEMS + r * 128 + c8]);
            lo[0] += (float)w[0]; lo[1] += (float)w[1];
            lo[2] += (float)w[2]; lo[3] += (float)w[3];
            hi[0] += (float)w[4]; hi[1] += (float)w[5];
            hi[2] += (float)w[6]; hi[3] += (float)w[7];
        }
        __builtin_nontemporal_store(lo, reinterpret_cast<v4f*>(&cp[(long)r * NN + c8]));
        __builtin_nontemporal_store(hi, reinterpret_cast<v4f*>(&cp[(long)r * NN + c8 + 4]));
    }
}

// ---------------- fallback (ws too small): fused convert-stage kernel -------
#define LDST 40
__global__ __launch_bounds__(256)
void trimm_fb(const float* __restrict__ A, const float* __restrict__ B,
              float* __restrict__ C) {
    const int id = blockIdx.x, t = threadIdx.x;
    if (id >= NUPPER) {
        int z = id - NUPPER;
        int bi = 1;
        while (((bi + 1) * bi) / 2 <= z) ++bi;
        int bj = z - (bi * (bi - 1)) / 2;
        const long brow = (long)bi * 128, bcol = (long)bj * 128;
        const v4f zv = (v4f){0.f, 0.f, 0.f, 0.f};
        #pragma unroll
        for (int i = 0; i < 16; ++i) {
            int s = i * 256 + t, r = s >> 5, c4 = (s & 31) << 2;
            *reinterpret_cast<v4f*>(&C[(brow + r) * NN + bcol + c4]) = zv;
        }
        return;
    }
    int q = (NUPPER - 1) - id;
    int d = 0;
    while (d < 31 && 32 * (d + 1) - (d + 1) * d / 2 <= q) ++d;
    const int bi = q - (32 * d - d * (d - 1) / 2);
    const int bj = bi + d;
    const long brow = (long)bi * 128, bcol = (long)bj * 128;
    __shared__ __bf16 As[128][LDST];
    __shared__ __bf16 Bs[128][LDST];
    const int lane = t & 63, wave = t >> 6;
    const int wm = (wave >> 1) * 64, wn = (wave & 1) * 64;
    const int l15 = lane & 15, g = lane >> 4;
    const int arow = t >> 3, akc = (t & 7) << 2;
    const int bn = t & 31, bkc = (t >> 5) << 2;
    v4f acc[4][4];
    #pragma unroll
    for (int mf = 0; mf < 4; ++mf)
        #pragma unroll
        for (int nf = 0; nf < 4; ++nf) acc[mf][nf] = (v4f){0.f,0.f,0.f,0.f};
    const long k0 = brow;
    const int nt = (d + 1) * 4;
    for (int tk = 0; tk < nt; ++tk) {
        const long kt = k0 + (long)tk * 32;
        #pragma unroll
        for (int i = 0; i < 4; ++i) {
            v4f a4 = *reinterpret_cast<const v4f*>(
                &A[(brow + arow + 32 * i) * NN + kt + akc]);
            v4bf pk;
            pk[0]=(__bf16)a4[0]; pk[1]=(__bf16)a4[1]; pk[2]=(__bf16)a4[2]; pk[3]=(__bf16)a4[3];
            *reinterpret_cast<v4bf*>(&As[arow + 32 * i][akc]) = pk;
        }
        {
            float tmp[4][4];
            #pragma unroll
            for (int jj = 0; jj < 4; ++jj) {
                const float* Brow = B + (kt + bkc + jj) * NN + bcol + bn;
                #pragma unroll
                for (int j = 0; j < 4; ++j) tmp[j][jj] = Brow[32 * j];
            }
            #pragma unroll
            for (int j = 0; j < 4; ++j) {
                v4bf pk;
                pk[0]=(__bf16)tmp[j][0]; pk[1]=(__bf16)tmp[j][1];
                pk[2]=(__bf16)tmp[j][2]; pk[3]=(__bf16)tmp[j][3];
                *reinterpret_cast<v4bf*>(&Bs[bn + 32 * j][bkc]) = pk;
            }
        }
        __syncthreads();
        v8bf af[4], bfr[4];
        #pragma unroll
        for (int mf = 0; mf < 4; ++mf)
            af[mf] = *reinterpret_cast<const v8bf*>(&As[wm + mf*16 + l15][g*8]);
        #pragma unroll
        for (int nf = 0; nf < 4; ++nf)
            bfr[nf] = *reinterpret_cast<const v8bf*>(&Bs[wn + nf*16 + l15][g*8]);
        #pragma unroll
        for (int mf = 0; mf < 4; ++mf)
            #pragma unroll
            for (int nf = 0; nf < 4; ++nf)
                acc[mf][nf] = __builtin_amdgcn_mfma_f32_16x16x32_bf16(
                    af[mf], bfr[nf], acc[mf][nf], 0, 0, 0);
        __syncthreads();
    }
    #pragma unroll
    for (int mf = 0; mf < 4; ++mf)
        #pragma unroll
        for (int nf = 0; nf < 4; ++nf) {
            long row = brow + wm + mf * 16 + g * 4;
            long col = bcol + wn + nf * 16 + l15;
            #pragma unroll
            for (int r = 0; r < 4; ++r)
                C[(row + r) * NN + col] = acc[mf][nf][r];
        }
}

static void split_counts(int umax, int* nwork, int* slots) {
    int w = 0, s = 0;
    for (int d = 0; d < 32; ++d) {
        int S = (d + umax) / umax;
        w += (32 - d) * S;
        s += (32 - d) * (S - 1);
    }
    *nwork = w; *slots = s;
}

extern "C" void kernel_launch(void* const* d_in, const int* in_sizes, int n_in,
                              void* d_out, int out_size, void* d_ws, size_t ws_size,
                              hipStream_t stream) {
    const float* A = (const float*)d_in[0];
    const float* B = (const float*)d_in[1];
    float* C = (float*)d_out;

    const size_t needAB = 2UL * NUPPER * BLK_ELEMS * sizeof(__bf16);  // ~33 MB

    // pick the finest split the workspace allows
    const int cand[2] = {16, 1000};
    int umax = 0, nwork = 0, slots = 0;
    for (int i = 0; i < 2; ++i) {
        int w, s;
        split_counts(cand[i], &w, &s);
        size_t need = needAB + (size_t)s * BLK_ELEMS * sizeof(__bf16);
        if (ws_size >= need) { umax = cand[i]; nwork = w; slots = s; break; }
    }

    if (umax) {
        __bf16* Apk = (__bf16*)d_ws;
        __bf16* Bpk = Apk + (size_t)NUPPER * BLK_ELEMS;
        __bf16* part = Bpk + (size_t)NUPPER * BLK_ELEMS;
        trimm_prep<<<dim3(2 * NUPPER + NLOWER), 256, 0, stream>>>(A, B, C, Apk, Bpk);
        trimm_mm<<<dim3(nwork), 256, 0, stream>>>(Apk, Bpk, C, part, umax);
        if (slots > 0)
            trimm_merge<<<dim3(NUPPER), 256, 0, stream>>>(C, part, umax);
    } else {
        trimm_fb<<<dim3(NUPPER + NLOWER), 256, 0, stream>>>(A, B, C);
    }
}